// Round 14
// baseline (17.811 us; speedup 1.0000x reference)
//
#include <hip/hip_runtime.h>

constexpr int B  = 2;
constexpr int L  = 256;
constexpr int Dd = 512;
constexpr int Hh = 256;
constexpr int Oo = 16;
constexpr int BL = B * L;
constexpr int NBO = B * Oo;          // 32
constexpr int SLAB = NBO * L;        // 8192 floats per partial slot

__device__ __forceinline__ float leaky(const float v) {
    return (v >= 0.f) ? v : 0.1f * v;
}
__device__ __forceinline__ void fma4(float& acc, const float4 a, const float4 b) {
    acc = fmaf(a.x, b.x, acc);
    acc = fmaf(a.y, b.y, acc);
    acc = fmaf(a.z, b.z, acc);
    acc = fmaf(a.w, b.w, acc);
}

// Sum across each row-of-16 lanes using DPP row-rotates (VALU pipe, not DS).
__device__ __forceinline__ float red16(float v) {
    v += __int_as_float(__builtin_amdgcn_update_dpp(
            0, __float_as_int(v), 0x128, 0xF, 0xF, true)); // row_ror:8
    v += __int_as_float(__builtin_amdgcn_update_dpp(
            0, __float_as_int(v), 0x124, 0xF, 0xF, true)); // row_ror:4
    v += __int_as_float(__builtin_amdgcn_update_dpp(
            0, __float_as_int(v), 0x122, 0xF, 0xF, true)); // row_ror:2
    v += __int_as_float(__builtin_amdgcn_update_dpp(
            0, __float_as_int(v), 0x121, 0xF, 0xF, true)); // row_ror:1
    return v;
}
// lane ^ 1 exchange-add via DPP quad_perm(1,0,3,2) — VALU pipe.
__device__ __forceinline__ float addx1(float v) {
    return v + __int_as_float(__builtin_amdgcn_update_dpp(
            0, __float_as_int(v), 0xB1, 0xF, 0xF, true));
}

// ---------------------------------------------------------------------------
// K1: fused MLP + partial projection.
// vs R13: (1) k-loop W loads software-pipelined 1 step ahead (L2 latency
// hides under the 128-FMA block); (2) Phase B uses all 256 threads
// (o=t>>4, r=(t>>1)&7, kh=t&1; DPP lane^1 combine; kh=0 writes — same
// 32B-burst pattern as R12).
// grid = (64 rowsets of 8, 4 h-chunks of 64, 2 matrices) = 512 blocks,
// 256 thr, 2 blocks/CU.
// ---------------------------------------------------------------------------
__global__ __launch_bounds__(256, 2) void mlp_proj_kernel(
    const float* __restrict__ x,
    const float* __restrict__ W1, const float* __restrict__ b1,
    const float* __restrict__ W2, const float* __restrict__ b2,
    const float* __restrict__ Wf,
    float* __restrict__ PA, float* __restrict__ PB, float* __restrict__ PD)
{
    const int rs = blockIdx.x;   // rowset: 8 bl-rows
    const int hc = blockIdx.y;   // h-chunk: 64 h
    const int m  = blockIdx.z;
    const float* __restrict__ W  = m ? W2 : W1;
    const float* __restrict__ bb = m ? b2 : b1;

    __shared__ float xs[8 * Dd];       // 16 KB
    __shared__ float hbuf[8][68];      // padded: conflict-free Phase-B reads
    const int t = threadIdx.x;
    {
        const float4* xg = reinterpret_cast<const float4*>(x + (size_t)rs * 8 * Dd);
        float4* s4 = reinterpret_cast<float4*>(xs);
        #pragma unroll
        for (int i = 0; i < 4; ++i) s4[t + 256 * i] = xg[t + 256 * i];
    }
    __syncthreads();

    const int wave = t >> 6, lane = t & 63, g = lane >> 4, kl = lane & 15;
    const int h0 = hc * 64 + wave * 16 + g * 4;

    const float4* w0 = reinterpret_cast<const float4*>(W + (size_t)(h0 + 0) * Dd);
    const float4* w1 = reinterpret_cast<const float4*>(W + (size_t)(h0 + 1) * Dd);
    const float4* w2 = reinterpret_cast<const float4*>(W + (size_t)(h0 + 2) * Dd);
    const float4* w3 = reinterpret_cast<const float4*>(W + (size_t)(h0 + 3) * Dd);
    const float4* xs4 = reinterpret_cast<const float4*>(xs);

    float acc[8][4];
    #pragma unroll
    for (int r = 0; r < 8; ++r)
        #pragma unroll
        for (int j = 0; j < 4; ++j) acc[r][j] = 0.f;

    // Software-pipelined k-loop: W for step s+1 in flight during step s.
    float4 wa = w0[kl], wb_ = w1[kl], wc = w2[kl], wd = w3[kl];
    #pragma unroll
    for (int s = 0; s < 8; ++s) {
        float4 na, nb, nc, nd;
        if (s < 7) {
            const int kn = (s + 1) * 16 + kl;
            na = w0[kn]; nb = w1[kn]; nc = w2[kn]; nd = w3[kn];
        }
        const int ko = s * 16 + kl;
        #pragma unroll
        for (int r = 0; r < 8; ++r) {
            const float4 xv = xs4[r * 128 + ko];
            fma4(acc[r][0], xv, wa);
            fma4(acc[r][1], xv, wb_);
            fma4(acc[r][2], xv, wc);
            fma4(acc[r][3], xv, wd);
        }
        if (s < 7) { wa = na; wb_ = nb; wc = nc; wd = nd; }
    }

    #pragma unroll
    for (int r = 0; r < 8; ++r)
        #pragma unroll
        for (int j = 0; j < 4; ++j)
            acc[r][j] = red16(acc[r][j]);

    if (kl == 0) {
        const float4 bv = *reinterpret_cast<const float4*>(bb + h0);
        const int hl = wave * 16 + g * 4;
        #pragma unroll
        for (int r = 0; r < 8; ++r) {
            float4 o;
            o.x = leaky(acc[r][0] + bv.x);
            o.y = leaky(acc[r][1] + bv.y);
            o.z = leaky(acc[r][2] + bv.z);
            o.w = leaky(acc[r][3] + bv.w);
            *reinterpret_cast<float4*>(&hbuf[r][hl]) = o;
        }
    }
    __syncthreads();

    // Phase B: all 256 threads. o = t>>4, r = (t>>1)&7, kh = t&1 (k-half).
    // Lane pair (kh=0,1) covers the 64-h slice; DPP lane^1 combine.
    {
        const int o = t >> 4, r = (t >> 1) & 7, kh = t & 1;
        const float* wfo = Wf + (size_t)o * (3 * Hh) + hc * 64 + kh * 32;
        const float4* wf1 = reinterpret_cast<const float4*>(wfo);
        const float4* wf2 = reinterpret_cast<const float4*>(wfo + Hh);
        const float4* wf3 = reinterpret_cast<const float4*>(wfo + 2 * Hh);
        const float4* hv  = reinterpret_cast<const float4*>(&hbuf[r][kh * 32]);

        float s1 = 0.f, s2 = 0.f, s3 = 0.f;
        #pragma unroll
        for (int k = 0; k < 8; ++k) {
            const float4 h4 = hv[k];
            fma4(s1, wf1[k], h4);
            fma4(s2, wf2[k], h4);
            if (m == 0) fma4(s3, wf3[k], h4);
        }
        s1 = addx1(s1);
        s2 = addx1(s2);
        if (m == 0) s3 = addx1(s3);

        if (kh == 0) {
            const int bl = rs * 8 + r;
            const int b = bl >> 8, l = bl & 255;
            const size_t idx = ((size_t)(b * Oo + o)) * L + l;
            if (m == 0) {
                PA[(size_t)hc * SLAB + idx] = s1;
                PB[(size_t)hc * SLAB + idx] = 0.5f * s2;
                PD[(size_t)hc * SLAB + idx] = s3;
            } else {
                PA[(size_t)(4 + hc) * SLAB + idx] = 0.5f * s2;
                PB[(size_t)(4 + hc) * SLAB + idx] = -s1;
            }
        }
    }
}

// ---------------------------------------------------------------------------
// K2: partial-reduce + scan + epilogue (byte-identical to R13).
// grid = 32 bo x 8 i-chunks = 256 blocks, 256 thr.
//   out[bo,i,j] = A[j] + Bv[i] + bf[o] + (C[j]-C[i-1])*rcp(j-i+1+1e-9)
// i = j+1 numerator exactly 0 (identical stored C values) -> no blowup.
// ---------------------------------------------------------------------------
__global__ __launch_bounds__(256) void out_kernel(
    const float* __restrict__ PA, const float* __restrict__ PB,
    const float* __restrict__ PD, const float* __restrict__ bf,
    float* __restrict__ out)
{
    const int bo = blockIdx.x >> 3;    // 0..31
    const int ig = blockIdx.x & 7;     // i-chunk of 32
    const int t  = threadIdx.x;

    __shared__ float Asm[L], Bsm[L], ca[L], cb[L];
    {
        float a = 0.f, bsum = 0.f, d = 0.f;
        #pragma unroll
        for (int s = 0; s < 8; ++s) {
            a    += PA[(size_t)s * SLAB + (size_t)bo * L + t];
            bsum += PB[(size_t)s * SLAB + (size_t)bo * L + t];
        }
        #pragma unroll
        for (int s = 0; s < 4; ++s)
            d += PD[(size_t)s * SLAB + (size_t)bo * L + t];
        Asm[t] = a; Bsm[t] = bsum; ca[t] = d;
    }
    __syncthreads();

    // Wave-0 scan: inclusive prefix of ca[0..255] -> cb[0..255].
    if (t < 64) {
        const float4 v = *reinterpret_cast<const float4*>(&ca[4 * t]);
        const float s0 = v.x;
        const float s1 = s0 + v.y;
        const float s2 = s1 + v.z;
        const float s3 = s2 + v.w;          // lane's inclusive total
        float tot = s3;
        #pragma unroll
        for (int off = 1; off < 64; off <<= 1) {
            const float u = __shfl_up(tot, off);
            tot = (t >= off) ? tot + u : tot;
        }
        const float excl = tot - s3;        // exclusive prefix of lane totals
        float4 c;
        c.x = excl + s0; c.y = excl + s1; c.z = excl + s2; c.w = excl + s3;
        *reinterpret_cast<float4*>(&cb[4 * t]) = c;
    }
    __syncthreads();
    // cb[l] = inclusive prefix C[l]

    const float bfv = bf[bo & (Oo - 1)];
    const int j0 = (t & 63) * 4;
    const int is = t >> 6;

    const float4 Av = *reinterpret_cast<const float4*>(Asm + j0);
    const float4 Cv = *reinterpret_cast<const float4*>(cb + j0);

    #pragma unroll
    for (int ii = 0; ii < 8; ++ii) {
        const int i = ig * 32 + is * 8 + ii;
        const float cp   = (i > 0) ? cb[i - 1] : 0.f;
        const float base = Bsm[i] + bfv;
        float4 r;
        r.x = Av.x + base + (Cv.x - cp) * __builtin_amdgcn_rcpf((float)(j0 + 0 - i + 1) + 1e-9f);
        r.y = Av.y + base + (Cv.y - cp) * __builtin_amdgcn_rcpf((float)(j0 + 1 - i + 1) + 1e-9f);
        r.z = Av.z + base + (Cv.z - cp) * __builtin_amdgcn_rcpf((float)(j0 + 2 - i + 1) + 1e-9f);
        r.w = Av.w + base + (Cv.w - cp) * __builtin_amdgcn_rcpf((float)(j0 + 3 - i + 1) + 1e-9f);
        *reinterpret_cast<float4*>(out + ((size_t)bo * L + i) * L + j0) = r;
    }
}

// ---------------------------------------------------------------------------
extern "C" void kernel_launch(void* const* d_in, const int* in_sizes, int n_in,
                              void* d_out, int out_size, void* d_ws, size_t ws_size,
                              hipStream_t stream)
{
    const float* x  = (const float*)d_in[0];
    const float* W1 = (const float*)d_in[1];
    const float* b1 = (const float*)d_in[2];
    const float* W2 = (const float*)d_in[3];
    const float* b2 = (const float*)d_in[4];
    const float* Wf = (const float*)d_in[5];
    const float* bf = (const float*)d_in[6];
    float* out = (float*)d_out;

    float* ws = (float*)d_ws;
    float* PA = ws;                       // 8 * SLAB
    float* PB = PA + 8 * (size_t)SLAB;    // 8 * SLAB
    float* PD = PB + 8 * (size_t)SLAB;    // 4 * SLAB

    hipLaunchKernelGGL(mlp_proj_kernel, dim3(BL / 8, 4, 2), dim3(256), 0, stream,
                       x, W1, b1, W2, b2, Wf, PA, PB, PD);
    hipLaunchKernelGGL(out_kernel, dim3(NBO * 8), dim3(256), 0, stream,
                       PA, PB, PD, bf, out);
}

// Round 15
// 17.337 us; speedup vs baseline: 1.0273x; 1.0273x over previous
//
#include <hip/hip_runtime.h>

constexpr int B  = 2;
constexpr int L  = 256;
constexpr int Dd = 512;
constexpr int Hh = 256;
constexpr int Oo = 16;
constexpr int BL = B * L;
constexpr int NBO = B * Oo;          // 32
constexpr int SLAB = NBO * L;        // 8192 floats per partial slot

__device__ __forceinline__ float leaky(const float v) {
    return (v >= 0.f) ? v : 0.1f * v;
}
__device__ __forceinline__ void fma4(float& acc, const float4 a, const float4 b) {
    acc = fmaf(a.x, b.x, acc);
    acc = fmaf(a.y, b.y, acc);
    acc = fmaf(a.z, b.z, acc);
    acc = fmaf(a.w, b.w, acc);
}

// Sum across each row-of-16 lanes using DPP row-rotates (VALU pipe, not DS).
__device__ __forceinline__ float red16(float v) {
    v += __int_as_float(__builtin_amdgcn_update_dpp(
            0, __float_as_int(v), 0x128, 0xF, 0xF, true)); // row_ror:8
    v += __int_as_float(__builtin_amdgcn_update_dpp(
            0, __float_as_int(v), 0x124, 0xF, 0xF, true)); // row_ror:4
    v += __int_as_float(__builtin_amdgcn_update_dpp(
            0, __float_as_int(v), 0x122, 0xF, 0xF, true)); // row_ror:2
    v += __int_as_float(__builtin_amdgcn_update_dpp(
            0, __float_as_int(v), 0x121, 0xF, 0xF, true)); // row_ror:1
    return v;
}

// ---------------------------------------------------------------------------
// K1: fused MLP + partial projection — R13 configuration (best: 17.4us).
// grid = (64 rowsets of 8, 4 h-chunks of 64, 2 matrices) = 512 blocks,
// 256 thr, 2 blocks/CU. Phase-B map (o=t>>3, r=t&7): 32B coalesced bursts.
// ---------------------------------------------------------------------------
__global__ __launch_bounds__(256, 2) void mlp_proj_kernel(
    const float* __restrict__ x,
    const float* __restrict__ W1, const float* __restrict__ b1,
    const float* __restrict__ W2, const float* __restrict__ b2,
    const float* __restrict__ Wf,
    float* __restrict__ PA, float* __restrict__ PB, float* __restrict__ PD)
{
    const int rs = blockIdx.x;   // rowset: 8 bl-rows
    const int hc = blockIdx.y;   // h-chunk: 64 h
    const int m  = blockIdx.z;
    const float* __restrict__ W  = m ? W2 : W1;
    const float* __restrict__ bb = m ? b2 : b1;

    __shared__ float xs[8 * Dd];       // 16 KB
    __shared__ float hbuf[8][68];      // padded: conflict-free Phase-B reads
    const int t = threadIdx.x;
    {
        const float4* xg = reinterpret_cast<const float4*>(x + (size_t)rs * 8 * Dd);
        float4* s4 = reinterpret_cast<float4*>(xs);
        #pragma unroll
        for (int i = 0; i < 4; ++i) s4[t + 256 * i] = xg[t + 256 * i];
    }
    __syncthreads();

    const int wave = t >> 6, lane = t & 63, g = lane >> 4, kl = lane & 15;
    const int h0 = hc * 64 + wave * 16 + g * 4;

    const float4* w0 = reinterpret_cast<const float4*>(W + (size_t)(h0 + 0) * Dd);
    const float4* w1 = reinterpret_cast<const float4*>(W + (size_t)(h0 + 1) * Dd);
    const float4* w2 = reinterpret_cast<const float4*>(W + (size_t)(h0 + 2) * Dd);
    const float4* w3 = reinterpret_cast<const float4*>(W + (size_t)(h0 + 3) * Dd);
    const float4* xs4 = reinterpret_cast<const float4*>(xs);

    float acc[8][4];
    #pragma unroll
    for (int r = 0; r < 8; ++r)
        #pragma unroll
        for (int j = 0; j < 4; ++j) acc[r][j] = 0.f;

    #pragma unroll
    for (int s = 0; s < 8; ++s) {
        const int ko = s * 16 + kl;
        const float4 a = w0[ko], b_ = w1[ko], c = w2[ko], d = w3[ko];
        #pragma unroll
        for (int r = 0; r < 8; ++r) {
            const float4 xv = xs4[r * 128 + ko];
            fma4(acc[r][0], xv, a);
            fma4(acc[r][1], xv, b_);
            fma4(acc[r][2], xv, c);
            fma4(acc[r][3], xv, d);
        }
    }

    #pragma unroll
    for (int r = 0; r < 8; ++r)
        #pragma unroll
        for (int j = 0; j < 4; ++j)
            acc[r][j] = red16(acc[r][j]);

    if (kl == 0) {
        const float4 bv = *reinterpret_cast<const float4*>(bb + h0);
        const int hl = wave * 16 + g * 4;
        #pragma unroll
        for (int r = 0; r < 8; ++r) {
            float4 o;
            o.x = leaky(acc[r][0] + bv.x);
            o.y = leaky(acc[r][1] + bv.y);
            o.z = leaky(acc[r][2] + bv.z);
            o.w = leaky(acc[r][3] + bv.w);
            *reinterpret_cast<float4*>(&hbuf[r][hl]) = o;
        }
    }
    __syncthreads();

    // Phase B: o = t>>3, r = t&7 -> 8-lane groups write 8 consecutive l.
    if (t < 128) {
        const int o = t >> 3, r = t & 7;
        const float4* wf1 = reinterpret_cast<const float4*>(Wf + (size_t)o * (3 * Hh) + hc * 64);
        const float4* wf2 = reinterpret_cast<const float4*>(Wf + (size_t)o * (3 * Hh) + Hh + hc * 64);
        const float4* wf3 = reinterpret_cast<const float4*>(Wf + (size_t)o * (3 * Hh) + 2 * Hh + hc * 64);
        const float4* hv  = reinterpret_cast<const float4*>(&hbuf[r][0]);

        float s1 = 0.f, s2 = 0.f, s3 = 0.f;
        #pragma unroll
        for (int k = 0; k < 16; ++k) {
            const float4 h4 = hv[k];
            fma4(s1, wf1[k], h4);
            fma4(s2, wf2[k], h4);
            if (m == 0) fma4(s3, wf3[k], h4);
        }

        const int bl = rs * 8 + r;
        const int b = bl >> 8, l = bl & 255;
        const size_t idx = ((size_t)(b * Oo + o)) * L + l;
        if (m == 0) {
            PA[(size_t)hc * SLAB + idx] = s1;
            PB[(size_t)hc * SLAB + idx] = 0.5f * s2;
            PD[(size_t)hc * SLAB + idx] = s3;
        } else {
            PA[(size_t)(4 + hc) * SLAB + idx] = 0.5f * s2;
            PB[(size_t)(4 + hc) * SLAB + idx] = -s1;
        }
    }
}

// ---------------------------------------------------------------------------
// K2: partial-reduce + scan + epilogue (R13 configuration).
// grid = 32 bo x 8 i-chunks = 256 blocks, 256 thr.
// Scan: wave 0 only — 4 elems serial-in-lane + 6-step __shfl_up wave scan.
//   out[bo,i,j] = A[j] + Bv[i] + bf[o] + (C[j]-C[i-1])*rcp(j-i+1+1e-9)
// i = j+1 numerator exactly 0 (identical stored C values) -> no blowup.
// ---------------------------------------------------------------------------
__global__ __launch_bounds__(256) void out_kernel(
    const float* __restrict__ PA, const float* __restrict__ PB,
    const float* __restrict__ PD, const float* __restrict__ bf,
    float* __restrict__ out)
{
    const int bo = blockIdx.x >> 3;    // 0..31
    const int ig = blockIdx.x & 7;     // i-chunk of 32
    const int t  = threadIdx.x;

    __shared__ float Asm[L], Bsm[L], ca[L], cb[L];
    {
        float a = 0.f, bsum = 0.f, d = 0.f;
        #pragma unroll
        for (int s = 0; s < 8; ++s) {
            a    += PA[(size_t)s * SLAB + (size_t)bo * L + t];
            bsum += PB[(size_t)s * SLAB + (size_t)bo * L + t];
        }
        #pragma unroll
        for (int s = 0; s < 4; ++s)
            d += PD[(size_t)s * SLAB + (size_t)bo * L + t];
        Asm[t] = a; Bsm[t] = bsum; ca[t] = d;
    }
    __syncthreads();

    // Wave-0 scan: inclusive prefix of ca[0..255] -> cb[0..255].
    if (t < 64) {
        const float4 v = *reinterpret_cast<const float4*>(&ca[4 * t]);
        const float s0 = v.x;
        const float s1 = s0 + v.y;
        const float s2 = s1 + v.z;
        const float s3 = s2 + v.w;          // lane's inclusive total
        float tot = s3;
        #pragma unroll
        for (int off = 1; off < 64; off <<= 1) {
            const float u = __shfl_up(tot, off);
            tot = (t >= off) ? tot + u : tot;
        }
        const float excl = tot - s3;        // exclusive prefix of lane totals
        float4 c;
        c.x = excl + s0; c.y = excl + s1; c.z = excl + s2; c.w = excl + s3;
        *reinterpret_cast<float4*>(&cb[4 * t]) = c;
    }
    __syncthreads();
    // cb[l] = inclusive prefix C[l]

    const float bfv = bf[bo & (Oo - 1)];
    const int j0 = (t & 63) * 4;
    const int is = t >> 6;

    const float4 Av = *reinterpret_cast<const float4*>(Asm + j0);
    const float4 Cv = *reinterpret_cast<const float4*>(cb + j0);

    #pragma unroll
    for (int ii = 0; ii < 8; ++ii) {
        const int i = ig * 32 + is * 8 + ii;
        const float cp   = (i > 0) ? cb[i - 1] : 0.f;
        const float base = Bsm[i] + bfv;
        float4 r;
        r.x = Av.x + base + (Cv.x - cp) * __builtin_amdgcn_rcpf((float)(j0 + 0 - i + 1) + 1e-9f);
        r.y = Av.y + base + (Cv.y - cp) * __builtin_amdgcn_rcpf((float)(j0 + 1 - i + 1) + 1e-9f);
        r.z = Av.z + base + (Cv.z - cp) * __builtin_amdgcn_rcpf((float)(j0 + 2 - i + 1) + 1e-9f);
        r.w = Av.w + base + (Cv.w - cp) * __builtin_amdgcn_rcpf((float)(j0 + 3 - i + 1) + 1e-9f);
        *reinterpret_cast<float4*>(out + ((size_t)bo * L + i) * L + j0) = r;
    }
}

// ---------------------------------------------------------------------------
extern "C" void kernel_launch(void* const* d_in, const int* in_sizes, int n_in,
                              void* d_out, int out_size, void* d_ws, size_t ws_size,
                              hipStream_t stream)
{
    const float* x  = (const float*)d_in[0];
    const float* W1 = (const float*)d_in[1];
    const float* b1 = (const float*)d_in[2];
    const float* W2 = (const float*)d_in[3];
    const float* b2 = (const float*)d_in[4];
    const float* Wf = (const float*)d_in[5];
    const float* bf = (const float*)d_in[6];
    float* out = (float*)d_out;

    float* ws = (float*)d_ws;
    float* PA = ws;                       // 8 * SLAB
    float* PB = PA + 8 * (size_t)SLAB;    // 8 * SLAB
    float* PD = PB + 8 * (size_t)SLAB;    // 4 * SLAB

    hipLaunchKernelGGL(mlp_proj_kernel, dim3(BL / 8, 4, 2), dim3(256), 0, stream,
                       x, W1, b1, W2, b2, Wf, PA, PB, PD);
    hipLaunchKernelGGL(out_kernel, dim3(NBO * 8), dim3(256), 0, stream,
                       PA, PB, PD, bf, out);
}